// Round 8
// baseline (135.291 us; speedup 1.0000x reference)
//
#include <hip/hip_runtime.h>
#include <hip/hip_bf16.h>
#include <math.h>

typedef _Float16 h16;
typedef h16   v4h  __attribute__((ext_vector_type(4)));
typedef h16   v8h  __attribute__((ext_vector_type(8)));
typedef h16   h2   __attribute__((ext_vector_type(2)));
typedef float v4f  __attribute__((ext_vector_type(4)));
typedef float v16f __attribute__((ext_vector_type(16)));
typedef unsigned u32x2 __attribute__((ext_vector_type(2)));
typedef unsigned u32x4 __attribute__((ext_vector_type(4)));

#define T_SEQ 2048
#define BATCH 16
#define NTOK  (BATCH * T_SEQ)
#define C_DIM 64
#define N_H   4
#define HD    16
#define FF    128
#define EPS_LN 1e-5f
#define MFMA16 __builtin_amdgcn_mfma_f32_16x16x16f16
#define MFMA32 __builtin_amdgcn_mfma_f32_32x32x16_f16
#define QSCALE (0.25f * 1.44269504089f)   // hd^-0.5 * log2(e)

static __device__ __forceinline__ float fexp2(float x) {
#if __has_builtin(__builtin_amdgcn_exp2f)
    return __builtin_amdgcn_exp2f(x);
#else
    float r; asm volatile("v_exp_f32 %0, %1" : "=v"(r) : "v"(x)); return r;
#endif
}
static __device__ __forceinline__ float frcp(float x) {
#if __has_builtin(__builtin_amdgcn_rcpf)
    return __builtin_amdgcn_rcpf(x);
#else
    return 1.0f / x;
#endif
}
static __device__ __forceinline__ float frsq(float x) {
#if __has_builtin(__builtin_amdgcn_rsqf)
    return __builtin_amdgcn_rsqf(x);
#else
    return rsqrtf(x);
#endif
}
static __device__ __forceinline__ h2 pk2(float lo, float hi) {
    return __builtin_bit_cast(h2, __builtin_amdgcn_cvt_pkrtz(lo, hi));
}
static __device__ __forceinline__ float fdot2p(h2 a, float acc) {
#if __has_builtin(__builtin_amdgcn_fdot2)
    const h2 one2 = {(h16)1.0f, (h16)1.0f};
    return __builtin_amdgcn_fdot2(a, one2, acc, false);
#else
    return acc + (float)a[0] + (float)a[1];
#endif
}
static __device__ __forceinline__ unsigned bc(h2 x) {
    return __builtin_bit_cast(unsigned, x);
}

// ---------------------------------------------------------------------------
// Weight prep: fp32 -> f16 once.
// ---------------------------------------------------------------------------
__global__ __launch_bounds__(256) void prep_weights(
    const float* __restrict__ Wqkv, const float* __restrict__ Wproj,
    const float* __restrict__ W1,   const float* __restrict__ W2,
    h16* __restrict__ wq, h16* __restrict__ whp,
    h16* __restrict__ wh1, h16* __restrict__ wh2)
{
    int i = blockIdx.x * 256 + threadIdx.x;     // 0..8191
    const float* src; h16* dst; int off;
    if      (i < 3072) { src = Wqkv;  dst = wq;  off = i; }
    else if (i < 4096) { src = Wproj; dst = whp; off = i - 3072; }
    else if (i < 6144) { src = W1;    dst = wh1; off = i - 4096; }
    else               { src = W2;    dst = wh2; off = i - 6144; }
    v4f f = ((const v4f*)src)[off];
    v4h o; o[0]=(h16)f[0]; o[1]=(h16)f[1]; o[2]=(h16)f[2]; o[3]=(h16)f[3];
    ((v4h*)dst)[off] = o;
}

// ---------------------------------------------------------------------------
// qkv GEMM: x[32768,64] @ Wqkv^T -> q (pre-scaled) / k  f16 [b,h,t,16],
// vt f16 [b,h,16,t].  1 wave = 16 tokens.
// ---------------------------------------------------------------------------
__global__ __launch_bounds__(256) void qkv_gemm(
    const float* __restrict__ x, const h16* __restrict__ wq,
    h16* __restrict__ q, h16* __restrict__ k, h16* __restrict__ vt)
{
    int tid = threadIdx.x;
    int lane = tid & 63, w = tid >> 6;
    int lm = lane & 15, g4 = (lane >> 4) * 4;
    int t0 = (blockIdx.x * 4 + w) * 16;

    v4h af[4];
#pragma unroll
    for (int kt = 0; kt < 4; kt++) {
        v4f xv = *(const v4f*)(x + (size_t)(t0 + lm) * C_DIM + kt * 16 + g4);
        v4h c; c[0]=(h16)xv[0]; c[1]=(h16)xv[1]; c[2]=(h16)xv[2]; c[3]=(h16)xv[3];
        af[kt] = c;
    }
    int b = t0 >> 11, tl = t0 & (T_SEQ - 1);
#pragma unroll
    for (int n = 0; n < 12; n++) {
        v4f acc = {0.f, 0.f, 0.f, 0.f};
#pragma unroll
        for (int kt = 0; kt < 4; kt++)
            acc = MFMA16(af[kt], *(const v4h*)(wq + (n*16 + lm)*C_DIM + kt*16 + g4),
                         acc, 0, 0, 0);
        if (n < 4) {
            h16* qp = q + ((size_t)(b*N_H + n)*T_SEQ + tl + g4)*HD + lm;
#pragma unroll
            for (int r = 0; r < 4; r++) qp[r*HD] = (h16)(acc[r] * QSCALE);
        } else if (n < 8) {
            h16* kp = k + ((size_t)(b*N_H + (n-4))*T_SEQ + tl + g4)*HD + lm;
#pragma unroll
            for (int r = 0; r < 4; r++) kp[r*HD] = (h16)acc[r];
        } else {
            v4h pk;
#pragma unroll
            for (int r = 0; r < 4; r++) pk[r] = (h16)acc[r];
            *(v4h*)(vt + ((size_t)(b*N_H + (n-8))*HD + lm)*T_SEQ + tl + g4) = pk;
        }
    }
}

// ---------------------------------------------------------------------------
// Flash attention on 32x32x16 MFMA (gfx950-native), no-max softmax,
// K-split x2, register prefetch of next K/V tile.
// Wave = 32 queries x 1024 keys (khalf).  Per 32-key tile:
//   S^T = mfma32(Kfrag, Qfrag)          (1 MFMA; q=lane&31, key=crow(reg,hi))
//   P^T assembled via cvt_pkrtz + permlane32_swap (m214 pattern)
//   acc^T += mfma32(Vtfrag, P^T)        (2 MFMAs, K=16 each; D-rows>=16 unused)
// ---------------------------------------------------------------------------
__global__ __launch_bounds__(256, 4) void attn_mfma(
    const h16* __restrict__ q, const h16* __restrict__ k,
    const h16* __restrict__ vt, h16* __restrict__ a)
{
    int tid = threadIdx.x;
    int lane = tid & 63, w = tid >> 6;
    int l31 = lane & 31;
    int hi  = lane >> 5;
    int bid = blockIdx.x;
    int W = (bid & 7) * 256 + (bid >> 3);     // XCD swizzle, bijective over 2048
    int bh = W >> 5;                          // 0..63
    int q64 = W & 31;                         // 64-query tile index
    int q0 = q64 * 64 + (w & 1) * 32;
    int khalf = w >> 1;

    // Q B-frag: q-col = l31, d = 8*hi + i  (16B contiguous)
    v8h qf = *(const v8h*)(q + ((size_t)bh*T_SEQ + q0 + l31)*HD + 8*hi);

    // K A-frag base: key-row = l31 (+32 per tile), d = 8*hi + i
    const h16* kb = k  + ((size_t)bh*T_SEQ + khalf*1024 + l31)*HD + 8*hi;
    // V A-frag base: d-row = lane&15 (rows>=16 unused by construction), keys contiguous
    const h16* vb = vt + ((size_t)bh*HD + (lane & 15))*T_SEQ + khalf*1024 + 8*hi;

    const v16f z16 = {0,0,0,0,0,0,0,0,0,0,0,0,0,0,0,0};
    v16f acc1 = z16, acc2 = z16;
    float lsum = 0.f;

    v8h kf  = *(const v8h*)kb;
    v8h vf1 = *(const v8h*)vb;
    v8h vf2 = *(const v8h*)(vb + 16);

    for (int t = 0; t < 32; t++) {
        // prefetch tile t+1 (t=31 over-read lands in mapped ws, unused)
        v8h kfn  = *(const v8h*)(kb + (size_t)(t+1)*32*HD);
        v8h vf1n = *(const v8h*)(vb + (t+1)*32);
        v8h vf2n = *(const v8h*)(vb + (t+1)*32 + 16);

        v16f s = MFMA32(kf, qf, z16, 0, 0, 0);

        float e0  = fexp2(s[0]),  e1  = fexp2(s[1]),  e2  = fexp2(s[2]),  e3  = fexp2(s[3]);
        float e4  = fexp2(s[4]),  e5  = fexp2(s[5]),  e6  = fexp2(s[6]),  e7  = fexp2(s[7]);
        float e8  = fexp2(s[8]),  e9  = fexp2(s[9]),  e10 = fexp2(s[10]), e11 = fexp2(s[11]);
        float e12 = fexp2(s[12]), e13 = fexp2(s[13]), e14 = fexp2(s[14]), e15 = fexp2(s[15]);

        h2 w0 = pk2(e0, e1),  w1 = pk2(e2, e3),  w2 = pk2(e4, e5),  w3 = pk2(e6, e7);
        h2 w4 = pk2(e8, e9),  w5 = pk2(e10,e11), w6 = pk2(e12,e13), w7 = pk2(e14,e15);

        lsum = fdot2p(w0, lsum); lsum = fdot2p(w1, lsum);
        lsum = fdot2p(w2, lsum); lsum = fdot2p(w3, lsum);
        lsum = fdot2p(w4, lsum); lsum = fdot2p(w5, lsum);
        lsum = fdot2p(w6, lsum); lsum = fdot2p(w7, lsum);

        // one swap fills two B-words: first={lo:w_a.lo, hi:w_b.lo}, second={lo:w_a.hi, hi:w_b.hi}
        u32x2 r02 = __builtin_amdgcn_permlane32_swap(bc(w0), bc(w2), false, false);
        u32x2 r13 = __builtin_amdgcn_permlane32_swap(bc(w1), bc(w3), false, false);
        u32x2 r46 = __builtin_amdgcn_permlane32_swap(bc(w4), bc(w6), false, false);
        u32x2 r57 = __builtin_amdgcn_permlane32_swap(bc(w5), bc(w7), false, false);

        u32x4 pb1; pb1[0] = r02[0]; pb1[1] = r13[0]; pb1[2] = r02[1]; pb1[3] = r13[1];
        u32x4 pb2; pb2[0] = r46[0]; pb2[1] = r57[0]; pb2[2] = r46[1]; pb2[3] = r57[1];

        acc1 = MFMA32(vf1, __builtin_bit_cast(v8h, pb1), acc1, 0, 0, 0);
        acc2 = MFMA32(vf2, __builtin_bit_cast(v8h, pb2), acc2, 0, 0, 0);

        kf = kfn; vf1 = vf1n; vf2 = vf2n;
    }

    // own-lane l covers 16 of 32 key-rows; partner lane (^32) has the rest
    float lfull = lsum + __shfl_xor(lsum, 32, 64);
    v16f accS = acc1 + acc2;

    // K-split merge via LDS: pure additive. Waves 2,3 publish; 0,1 combine+store.
    __shared__ float lds[2][64][9];
    if (w >= 2) {
        float* p = lds[w - 2][lane];
        p[0] = lfull;
#pragma unroll
        for (int r = 0; r < 8; r++) p[1 + r] = accS[r];
    }
    __syncthreads();
    if (w < 2) {
        const float* p = lds[w][lane];
        float inv = frcp(lfull + p[0]);
        int b = bh >> 2, h = bh & 3;
        // reg r<4: d = r + 4*hi ; reg 4..7: d = 8 + (r&3) + 4*hi ; q = l31
        v4h o1, o2;
#pragma unroll
        for (int r = 0; r < 4; r++) o1[r] = (h16)((accS[r]   + p[1 + r])   * inv);
#pragma unroll
        for (int r = 0; r < 4; r++) o2[r] = (h16)((accS[4+r] + p[5 + r])   * inv);
        h16* ab = a + ((size_t)(b*T_SEQ) + q0 + l31)*C_DIM + h*HD;
        *(v4h*)(ab + 4*hi)     = o1;
        *(v4h*)(ab + 8 + 4*hi) = o2;
    }
}

// ---------------------------------------------------------------------------
// Fused tail: proj + residual + LN1 + FFN1 + ReLU + FFN2 + residual + LN2.
// ---------------------------------------------------------------------------
__global__ __launch_bounds__(256) void tail_fused(
    const h16* __restrict__ a, const float* __restrict__ x,
    const h16* __restrict__ whp, const h16* __restrict__ wh1, const h16* __restrict__ wh2,
    const float* __restrict__ b1, const float* __restrict__ b2,
    const float* __restrict__ g1, const float* __restrict__ be1,
    const float* __restrict__ g2, const float* __restrict__ be2,
    float* __restrict__ out)
{
    int tid = threadIdx.x;
    int lane = tid & 63, w = tid >> 6;
    int lm = lane & 15, g4 = (lane >> 4) * 4;
    int t0 = (blockIdx.x * 4 + w) * 16;

    v4h af[4];
#pragma unroll
    for (int kt = 0; kt < 4; kt++)
        af[kt] = *(const v4h*)(a + (size_t)(t0 + lm)*C_DIM + kt*16 + g4);

    // ---- proj + residual + LN1 ----
    float rvn[4][4];
    v4h x1t[4];
    {
        v4f rv[4];
#pragma unroll
        for (int cn = 0; cn < 4; cn++) {
            v4f acc = {0.f, 0.f, 0.f, 0.f};
#pragma unroll
            for (int kt = 0; kt < 4; kt++)
                acc = MFMA16(*(const v4h*)(whp + (cn*16 + lm)*C_DIM + kt*16 + g4),
                             af[kt], acc, 0, 0, 0);
            v4f xr = *(const v4f*)(x + (size_t)(t0 + lm)*C_DIM + cn*16 + g4);
            rv[cn] = acc + xr;
        }
        float s = 0.f;
#pragma unroll
        for (int cn = 0; cn < 4; cn++)
#pragma unroll
            for (int i = 0; i < 4; i++) s += rv[cn][i];
        s += __shfl_xor(s, 16, 64); s += __shfl_xor(s, 32, 64);
        float mu = s * (1.f/64.f);
        float qs = 0.f;
#pragma unroll
        for (int cn = 0; cn < 4; cn++)
#pragma unroll
            for (int i = 0; i < 4; i++) { float d = rv[cn][i] - mu; qs += d*d; }
        qs += __shfl_xor(qs, 16, 64); qs += __shfl_xor(qs, 32, 64);
        float is = frsq(qs * (1.f/64.f) + EPS_LN);
#pragma unroll
        for (int cn = 0; cn < 4; cn++) {
            v4f g1v = *(const v4f*)(g1 + cn*16 + g4);
            v4f bev = *(const v4f*)(be1 + cn*16 + g4);
#pragma unroll
            for (int i = 0; i < 4; i++) {
                float vl = (rv[cn][i] - mu) * is * g1v[i] + bev[i];
                rvn[cn][i] = vl;
                x1t[cn][i] = (h16)vl;
            }
        }
    }
    __builtin_amdgcn_sched_barrier(0);

    // ---- FFN1 + ReLU ----
    v4h ht[8];
#pragma unroll
    for (int nf = 0; nf < 8; nf++) {
        v4f acc = {0.f, 0.f, 0.f, 0.f};
#pragma unroll
        for (int kt = 0; kt < 4; kt++)
            acc = MFMA16(*(const v4h*)(wh1 + (nf*16 + lm)*C_DIM + kt*16 + g4),
                         x1t[kt], acc, 0, 0, 0);
        v4f b1v = *(const v4f*)(b1 + nf*16 + g4);
#pragma unroll
        for (int i = 0; i < 4; i++) ht[nf][i] = (h16)fmaxf(acc[i] + b1v[i], 0.f);
    }
    __builtin_amdgcn_sched_barrier(0);

    // ---- FFN2 + residual + LN2 ----
    float yv[4][4];
#pragma unroll
    for (int cn = 0; cn < 4; cn++) {
        v4f acc = {0.f, 0.f, 0.f, 0.f};
#pragma unroll
        for (int kf2 = 0; kf2 < 8; kf2++)
            acc = MFMA16(*(const v4h*)(wh2 + (cn*16 + lm)*FF + kf2*16 + g4),
                         ht[kf2], acc, 0, 0, 0);
        v4f b2v = *(const v4f*)(b2 + cn*16 + g4);
#pragma unroll
        for (int i = 0; i < 4; i++) yv[cn][i] = acc[i] + b2v[i] + rvn[cn][i];
    }
    float s2 = 0.f;
#pragma unroll
    for (int cn = 0; cn < 4; cn++)
#pragma unroll
        for (int i = 0; i < 4; i++) s2 += yv[cn][i];
    s2 += __shfl_xor(s2, 16, 64); s2 += __shfl_xor(s2, 32, 64);
    float mu2 = s2 * (1.f/64.f);
    float qs2 = 0.f;
#pragma unroll
    for (int cn = 0; cn < 4; cn++)
#pragma unroll
        for (int i = 0; i < 4; i++) { float d = yv[cn][i] - mu2; qs2 += d*d; }
    qs2 += __shfl_xor(qs2, 16, 64); qs2 += __shfl_xor(qs2, 32, 64);
    float is2 = frsq(qs2 * (1.f/64.f) + EPS_LN);
#pragma unroll
    for (int cn = 0; cn < 4; cn++) {
        v4f g2v = *(const v4f*)(g2 + cn*16 + g4);
        v4f bev = *(const v4f*)(be2 + cn*16 + g4);
        v4f o;
#pragma unroll
        for (int i = 0; i < 4; i++) o[i] = (yv[cn][i] - mu2) * is2 * g2v[i] + bev[i];
        *(v4f*)(out + (size_t)(t0 + lm)*C_DIM + cn*16 + g4) = o;
    }
}

// ---------------------------------------------------------------------------
extern "C" void kernel_launch(void* const* d_in, const int* in_sizes, int n_in,
                              void* d_out, int out_size, void* d_ws, size_t ws_size,
                              hipStream_t stream)
{
    const float* x     = (const float*)d_in[0];
    const float* Wqkv  = (const float*)d_in[1];
    const float* Wproj = (const float*)d_in[2];
    const float* W1    = (const float*)d_in[3];
    const float* b1    = (const float*)d_in[4];
    const float* W2    = (const float*)d_in[5];
    const float* b2    = (const float*)d_in[6];
    const float* g1    = (const float*)d_in[7];
    const float* be1   = (const float*)d_in[8];
    const float* g2    = (const float*)d_in[9];
    const float* be2   = (const float*)d_in[10];
    float* out = (float*)d_out;

    const size_t perQ = (size_t)BATCH * N_H * T_SEQ * HD;   // 2M elements
    h16* q   = (h16*)d_ws;
    h16* kk  = q  + perQ;
    h16* vt  = kk + perQ;
    h16* a   = vt + perQ;
    h16* wq  = a  + (size_t)NTOK * C_DIM;
    h16* whp = wq  + 3 * C_DIM * C_DIM;
    h16* wh1 = whp + C_DIM * C_DIM;
    h16* wh2 = wh1 + FF * C_DIM;

    prep_weights<<<32,  256, 0, stream>>>(Wqkv, Wproj, W1, W2, wq, whp, wh1, wh2);
    qkv_gemm   <<<512,  256, 0, stream>>>(x, wq, q, kk, vt);
    attn_mfma  <<<2048, 256, 0, stream>>>(q, kk, vt, a);
    tail_fused <<<512,  256, 0, stream>>>(a, x, whp, wh1, wh2, b1, b2,
                                          g1, be1, g2, be2, out);
}

// Round 9
// 128.528 us; speedup vs baseline: 1.0526x; 1.0526x over previous
//
#include <hip/hip_runtime.h>
#include <hip/hip_bf16.h>
#include <math.h>

typedef _Float16 h16;
typedef h16   v4h __attribute__((ext_vector_type(4)));
typedef h16   h2  __attribute__((ext_vector_type(2)));
typedef float v4f __attribute__((ext_vector_type(4)));

#define T_SEQ 2048
#define BATCH 16
#define NTOK  (BATCH * T_SEQ)
#define C_DIM 64
#define N_H   4
#define HD    16
#define FF    128
#define EPS_LN 1e-5f
#define MFMA16 __builtin_amdgcn_mfma_f32_16x16x16f16
#define QSCALE (0.25f * 1.44269504089f)   // hd^-0.5 * log2(e)

static __device__ __forceinline__ float fexp2(float x) {
#if __has_builtin(__builtin_amdgcn_exp2f)
    return __builtin_amdgcn_exp2f(x);
#else
    float r; asm volatile("v_exp_f32 %0, %1" : "=v"(r) : "v"(x)); return r;
#endif
}
static __device__ __forceinline__ float frcp(float x) {
#if __has_builtin(__builtin_amdgcn_rcpf)
    return __builtin_amdgcn_rcpf(x);
#else
    return 1.0f / x;
#endif
}
static __device__ __forceinline__ float frsq(float x) {
#if __has_builtin(__builtin_amdgcn_rsqf)
    return __builtin_amdgcn_rsqf(x);
#else
    return rsqrtf(x);
#endif
}
static __device__ __forceinline__ h2 pk2(float lo, float hi) {
    return __builtin_bit_cast(h2, __builtin_amdgcn_cvt_pkrtz(lo, hi));
}
static __device__ __forceinline__ float fdot2p(h2 a, float acc) {
#if __has_builtin(__builtin_amdgcn_fdot2)
    const h2 one2 = {(h16)1.0f, (h16)1.0f};
    return __builtin_amdgcn_fdot2(a, one2, acc, false);
#else
    return acc + (float)a[0] + (float)a[1];
#endif
}
static __device__ __forceinline__ v4h cvt4(v4f f) {
    v4h r; r[0]=(h16)f[0]; r[1]=(h16)f[1]; r[2]=(h16)f[2]; r[3]=(h16)f[3];
    return r;
}

// ---------------------------------------------------------------------------
// qkv GEMM: x[32768,64] @ Wqkv^T -> q (pre-scaled) / k  f16 [b,h,t,16],
// vt f16 [b,h,16,t].  1 wave = 16 tokens. Weights converted inline (f32->f16).
// ---------------------------------------------------------------------------
__global__ __launch_bounds__(256) void qkv_gemm(
    const float* __restrict__ x, const float* __restrict__ Wqkv,
    h16* __restrict__ q, h16* __restrict__ k, h16* __restrict__ vt)
{
    int tid = threadIdx.x;
    int lane = tid & 63, w = tid >> 6;
    int lm = lane & 15, g4 = (lane >> 4) * 4;
    int t0 = (blockIdx.x * 4 + w) * 16;

    v4h af[4];
#pragma unroll
    for (int kt = 0; kt < 4; kt++)
        af[kt] = cvt4(*(const v4f*)(x + (size_t)(t0 + lm) * C_DIM + kt * 16 + g4));

    int b = t0 >> 11, tl = t0 & (T_SEQ - 1);
#pragma unroll
    for (int n = 0; n < 12; n++) {
        v4f acc = {0.f, 0.f, 0.f, 0.f};
#pragma unroll
        for (int kt = 0; kt < 4; kt++) {
            v4h bf = cvt4(*(const v4f*)(Wqkv + (n*16 + lm)*C_DIM + kt*16 + g4));
            acc = MFMA16(af[kt], bf, acc, 0, 0, 0);
        }
        if (n < 4) {
            h16* qp = q + ((size_t)(b*N_H + n)*T_SEQ + tl + g4)*HD + lm;
#pragma unroll
            for (int r = 0; r < 4; r++) qp[r*HD] = (h16)(acc[r] * QSCALE);
        } else if (n < 8) {
            h16* kp = k + ((size_t)(b*N_H + (n-4))*T_SEQ + tl + g4)*HD + lm;
#pragma unroll
            for (int r = 0; r < 4; r++) kp[r*HD] = (h16)acc[r];
        } else {
            v4h pk;
#pragma unroll
            for (int r = 0; r < 4; r++) pk[r] = (h16)acc[r];
            *(v4h*)(vt + ((size_t)(b*N_H + (n-8))*HD + lm)*T_SEQ + tl + g4) = pk;
        }
    }
}

// ---------------------------------------------------------------------------
// Flash attention (r7 structure): NO-MAX softmax, K-split x2,
// + explicit K-tile register prefetch, + s_setprio around compute cluster.
// Block = 4 waves over one (bh, 64-query tile):
//   wave w: q-subtile = w&1 (32 queries), key-half = w>>1 (1024 keys).
// ---------------------------------------------------------------------------
__global__ __launch_bounds__(256, 8) void attn_mfma(
    const h16* __restrict__ q, const h16* __restrict__ k,
    const h16* __restrict__ vt, h16* __restrict__ a)
{
    int tid = threadIdx.x;
    int lane = tid & 63, w = tid >> 6;
    int lm = lane & 15, g4 = (lane >> 4) * 4;
    int bid = blockIdx.x;
    int W = (bid & 7) * 256 + (bid >> 3);     // XCD swizzle, bijective over 2048
    int bh = W >> 5;                          // 0..63
    int q64 = W & 31;                         // 64-query tile
    int q0 = q64 * 64 + (w & 1) * 32;
    int khalf = w >> 1;

    v4h qf0 = *(const v4h*)(q + ((size_t)bh*T_SEQ + q0      + lm)*HD + g4);
    v4h qf1 = *(const v4h*)(q + ((size_t)bh*T_SEQ + q0 + 16 + lm)*HD + g4);
    const h16* kp = k  + ((size_t)bh*T_SEQ + khalf*1024 + lm)*HD + g4;
    const h16* vp = vt + ((size_t)bh*HD + lm)*T_SEQ + khalf*1024 + g4;

    v4f accA0={0,0,0,0}, accB0={0,0,0,0}, accA1={0,0,0,0}, accB1={0,0,0,0};
    float l0a = 0.f, l0b = 0.f, l1a = 0.f, l1b = 0.f;
    const v4f z = {0.f, 0.f, 0.f, 0.f};

    // K tile 0 preload (register prefetch rotation)
    v4h kf[4];
#pragma unroll
    for (int m = 0; m < 4; m++)
        kf[m] = *(const v4h*)(kp + (size_t)(16*m)*HD);

    for (int kt = 0; kt < 16; kt++) {
        // prefetch next K tile (kt=15 over-read lands in mapped ws, unused)
        v4h kfn[4];
#pragma unroll
        for (int m = 0; m < 4; m++)
            kfn[m] = *(const v4h*)(kp + (size_t)((kt+1)*64 + 16*m)*HD);
        // V tile in-line (latency partially hidden behind S-MFMA/exp chain)
        v4h vf[4];
#pragma unroll
        for (int m = 0; m < 4; m++)
            vf[m] = *(const v4h*)(vp + kt*64 + 16*m);

        __builtin_amdgcn_s_setprio(1);
#pragma unroll
        for (int m = 0; m < 4; m++) {
            v4f s0 = MFMA16(kf[m], qf0, z, 0, 0, 0);
            v4f s1 = MFMA16(kf[m], qf1, z, 0, 0, 0);
            h2 a0 = pk2(fexp2(s0[0]), fexp2(s0[1]));
            h2 b0 = pk2(fexp2(s0[2]), fexp2(s0[3]));
            h2 a1 = pk2(fexp2(s1[0]), fexp2(s1[1]));
            h2 b1 = pk2(fexp2(s1[2]), fexp2(s1[3]));
            l0a = fdot2p(a0, l0a); l0b = fdot2p(b0, l0b);
            l1a = fdot2p(a1, l1a); l1b = fdot2p(b1, l1b);
            v4h p0 = __builtin_shufflevector(a0, b0, 0, 1, 2, 3);
            v4h p1 = __builtin_shufflevector(a1, b1, 0, 1, 2, 3);
            if (m & 1) { accB0 = MFMA16(vf[m], p0, accB0, 0,0,0); accB1 = MFMA16(vf[m], p1, accB1, 0,0,0); }
            else       { accA0 = MFMA16(vf[m], p0, accA0, 0,0,0); accA1 = MFMA16(vf[m], p1, accA1, 0,0,0); }
        }
        __builtin_amdgcn_s_setprio(0);

#pragma unroll
        for (int m = 0; m < 4; m++) kf[m] = kfn[m];
    }

    // per-wave finalize: group-reduce l (column-uniform), sum acc pairs
    float l0 = l0a + l0b, l1 = l1a + l1b;
    l0 += __shfl_xor(l0, 16, 64); l0 += __shfl_xor(l0, 32, 64);
    l1 += __shfl_xor(l1, 16, 64); l1 += __shfl_xor(l1, 32, 64);
    v4f acc0 = accA0 + accB0, acc1 = accA1 + accB1;

    // K-split merge via LDS: pure additive (no max). Waves 2,3 publish.
    __shared__ float lds[2][64][13];
    if (w >= 2) {
        float* p = lds[w - 2][lane];
        p[0] = l0; p[1] = l1;
#pragma unroll
        for (int r = 0; r < 4; r++) { p[2 + r] = acc0[r]; p[6 + r] = acc1[r]; }
    }
    __syncthreads();
    if (w < 2) {
        const float* p = lds[w][lane];
        float inv0 = frcp(l0 + p[0]);
        float inv1 = frcp(l1 + p[1]);
        int b = bh >> 2, h = bh & 3;
        v4h o0, o1;
#pragma unroll
        for (int r = 0; r < 4; r++) {
            o0[r] = (h16)((acc0[r] + p[2 + r]) * inv0);
            o1[r] = (h16)((acc1[r] + p[6 + r]) * inv1);
        }
        *(v4h*)(a + ((size_t)(b*T_SEQ) + q0      + lm)*C_DIM + h*HD + g4) = o0;
        *(v4h*)(a + ((size_t)(b*T_SEQ) + q0 + 16 + lm)*C_DIM + h*HD + g4) = o1;
    }
}

// ---------------------------------------------------------------------------
// Fused tail: proj + residual + LN1 + FFN1 + ReLU + FFN2 + residual + LN2.
// Weights converted inline from f32 (no prep kernel).
// ---------------------------------------------------------------------------
__global__ __launch_bounds__(256) void tail_fused(
    const h16* __restrict__ a, const float* __restrict__ x,
    const float* __restrict__ Wproj, const float* __restrict__ W1, const float* __restrict__ W2,
    const float* __restrict__ b1, const float* __restrict__ b2,
    const float* __restrict__ g1, const float* __restrict__ be1,
    const float* __restrict__ g2, const float* __restrict__ be2,
    float* __restrict__ out)
{
    int tid = threadIdx.x;
    int lane = tid & 63, w = tid >> 6;
    int lm = lane & 15, g4 = (lane >> 4) * 4;
    int t0 = (blockIdx.x * 4 + w) * 16;

    v4h af[4];
#pragma unroll
    for (int kt = 0; kt < 4; kt++)
        af[kt] = *(const v4h*)(a + (size_t)(t0 + lm)*C_DIM + kt*16 + g4);

    // ---- proj + residual + LN1 ----
    float rvn[4][4];
    v4h x1t[4];
    {
        v4f rv[4];
#pragma unroll
        for (int cn = 0; cn < 4; cn++) {
            v4f acc = {0.f, 0.f, 0.f, 0.f};
#pragma unroll
            for (int kt = 0; kt < 4; kt++) {
                v4h bf = cvt4(*(const v4f*)(Wproj + (cn*16 + lm)*C_DIM + kt*16 + g4));
                acc = MFMA16(bf, af[kt], acc, 0, 0, 0);
            }
            v4f xr = *(const v4f*)(x + (size_t)(t0 + lm)*C_DIM + cn*16 + g4);
            rv[cn] = acc + xr;
        }
        float s = 0.f;
#pragma unroll
        for (int cn = 0; cn < 4; cn++)
#pragma unroll
            for (int i = 0; i < 4; i++) s += rv[cn][i];
        s += __shfl_xor(s, 16, 64); s += __shfl_xor(s, 32, 64);
        float mu = s * (1.f/64.f);
        float qs = 0.f;
#pragma unroll
        for (int cn = 0; cn < 4; cn++)
#pragma unroll
            for (int i = 0; i < 4; i++) { float d = rv[cn][i] - mu; qs += d*d; }
        qs += __shfl_xor(qs, 16, 64); qs += __shfl_xor(qs, 32, 64);
        float is = frsq(qs * (1.f/64.f) + EPS_LN);
#pragma unroll
        for (int cn = 0; cn < 4; cn++) {
            v4f g1v = *(const v4f*)(g1 + cn*16 + g4);
            v4f bev = *(const v4f*)(be1 + cn*16 + g4);
#pragma unroll
            for (int i = 0; i < 4; i++) {
                float vl = (rv[cn][i] - mu) * is * g1v[i] + bev[i];
                rvn[cn][i] = vl;
                x1t[cn][i] = (h16)vl;
            }
        }
    }
    __builtin_amdgcn_sched_barrier(0);

    // ---- FFN1 + ReLU ----
    v4h ht[8];
#pragma unroll
    for (int nf = 0; nf < 8; nf++) {
        v4f acc = {0.f, 0.f, 0.f, 0.f};
#pragma unroll
        for (int kt = 0; kt < 4; kt++) {
            v4h bf = cvt4(*(const v4f*)(W1 + (nf*16 + lm)*C_DIM + kt*16 + g4));
            acc = MFMA16(bf, x1t[kt], acc, 0, 0, 0);
        }
        v4f b1v = *(const v4f*)(b1 + nf*16 + g4);
#pragma unroll
        for (int i = 0; i < 4; i++) ht[nf][i] = (h16)fmaxf(acc[i] + b1v[i], 0.f);
    }
    __builtin_amdgcn_sched_barrier(0);

    // ---- FFN2 + residual + LN2 ----
    float yv[4][4];
#pragma unroll
    for (int cn = 0; cn < 4; cn++) {
        v4f acc = {0.f, 0.f, 0.f, 0.f};
#pragma unroll
        for (int kf2 = 0; kf2 < 8; kf2++) {
            v4h bf = cvt4(*(const v4f*)(W2 + (cn*16 + lm)*FF + kf2*16 + g4));
            acc = MFMA16(bf, ht[kf2], acc, 0, 0, 0);
        }
        v4f b2v = *(const v4f*)(b2 + cn*16 + g4);
#pragma unroll
        for (int i = 0; i < 4; i++) yv[cn][i] = acc[i] + b2v[i] + rvn[cn][i];
    }
    float s2 = 0.f;
#pragma unroll
    for (int cn = 0; cn < 4; cn++)
#pragma unroll
        for (int i = 0; i < 4; i++) s2 += yv[cn][i];
    s2 += __shfl_xor(s2, 16, 64); s2 += __shfl_xor(s2, 32, 64);
    float mu2 = s2 * (1.f/64.f);
    float qs2 = 0.f;
#pragma unroll
    for (int cn = 0; cn < 4; cn++)
#pragma unroll
        for (int i = 0; i < 4; i++) { float d = yv[cn][i] - mu2; qs2 += d*d; }
    qs2 += __shfl_xor(qs2, 16, 64); qs2 += __shfl_xor(qs2, 32, 64);
    float is2 = frsq(qs2 * (1.f/64.f) + EPS_LN);
#pragma unroll
    for (int cn = 0; cn < 4; cn++) {
        v4f g2v = *(const v4f*)(g2 + cn*16 + g4);
        v4f bev = *(const v4f*)(be2 + cn*16 + g4);
        v4f o;
#pragma unroll
        for (int i = 0; i < 4; i++) o[i] = (yv[cn][i] - mu2) * is2 * g2v[i] + bev[i];
        *(v4f*)(out + (size_t)(t0 + lm)*C_DIM + cn*16 + g4) = o;
    }
}

// ---------------------------------------------------------------------------
extern "C" void kernel_launch(void* const* d_in, const int* in_sizes, int n_in,
                              void* d_out, int out_size, void* d_ws, size_t ws_size,
                              hipStream_t stream)
{
    const float* x     = (const float*)d_in[0];
    const float* Wqkv  = (const float*)d_in[1];
    const float* Wproj = (const float*)d_in[2];
    const float* W1    = (const float*)d_in[3];
    const float* b1    = (const float*)d_in[4];
    const float* W2    = (const float*)d_in[5];
    const float* b2    = (const float*)d_in[6];
    const float* g1    = (const float*)d_in[7];
    const float* be1   = (const float*)d_in[8];
    const float* g2    = (const float*)d_in[9];
    const float* be2   = (const float*)d_in[10];
    float* out = (float*)d_out;

    const size_t perQ = (size_t)BATCH * N_H * T_SEQ * HD;   // 2M elements
    h16* q   = (h16*)d_ws;
    h16* kk  = q  + perQ;
    h16* vt  = kk + perQ;
    h16* a   = vt + perQ;

    qkv_gemm   <<<512,  256, 0, stream>>>(x, Wqkv, q, kk, vt);
    attn_mfma  <<<2048, 256, 0, stream>>>(q, kk, vt, a);
    tail_fused <<<512,  256, 0, stream>>>(a, x, Wproj, W1, W2, b1, b2,
                                          g1, be1, g2, be2, out);
}